// Round 7
// baseline (6319.146 us; speedup 1.0000x reference)
//
#include <hip/hip_runtime.h>
#include <stdint.h>

#define B_SZ   2048
#define T_ENC  168
#define TEMPD  128
#define HID    1024
#define M_DEC  48

typedef _Float16 f16;
typedef _Float16 half8 __attribute__((ext_vector_type(8)));
typedef float    f32x4 __attribute__((ext_vector_type(4)));

__device__ __forceinline__ float sigf(float x)   { return 1.0f / (1.0f + __expf(-x)); }
__device__ __forceinline__ float tanhf_(float x) { return 2.0f / (1.0f + __expf(-2.0f * x)) - 1.0f; }

// Direct global->LDS, 16B per lane. LDS ptr must be wave-uniform base.
__device__ __forceinline__ void gld16(const void* g, void* l) {
    __builtin_amdgcn_global_load_lds(
        (const __attribute__((address_space(1))) void*)g,
        (__attribute__((address_space(3))) void*)l, 16, 0, 0);
}

// ---------------------------------------------------------------------------
// prep_xseq: temp_seq [B][T][128] fp32 -> xseq [T][B][128] f16
// ---------------------------------------------------------------------------
__global__ void prep_xseq(const float* __restrict__ temp_seq, f16* __restrict__ xseq)
{
    size_t i4 = ((size_t)blockIdx.x * blockDim.x + threadIdx.x) * 4;
    size_t b  = i4 / (T_ENC * TEMPD);
    size_t r  = i4 - b * (T_ENC * TEMPD);
    size_t t  = r >> 7;
    size_t d  = r & 127;
    float4 v = *(const float4*)(temp_seq + i4);
    f16* o = xseq + ((t * B_SZ) + b) * TEMPD + d;
    o[0] = (f16)v.x; o[1] = (f16)v.y; o[2] = (f16)v.z; o[3] = (f16)v.w;
}

// ---------------------------------------------------------------------------
// prep_misc: merged f16 weights [4H][128+1024], fcW f16, biases, wlast
// ---------------------------------------------------------------------------
__global__ void prep_misc(
    const float* __restrict__ encWih, const float* __restrict__ encWhh,
    const float* __restrict__ decWih, const float* __restrict__ decWhh,
    const float* __restrict__ encbih, const float* __restrict__ encbhh,
    const float* __restrict__ decbih, const float* __restrict__ decbhh,
    const float* __restrict__ fcW,
    f16* __restrict__ Wenc, f16* __restrict__ Wdec0, f16* __restrict__ fcWh,
    float* __restrict__ enc_b, float* __restrict__ dec_b, float* __restrict__ wlast)
{
    const int NW = 4 * HID * (TEMPD + HID);
    for (int idx = blockIdx.x * blockDim.x + threadIdx.x; idx < NW;
         idx += gridDim.x * blockDim.x) {
        int j = idx / (TEMPD + HID);
        int k = idx - j * (TEMPD + HID);
        Wenc[idx]  = (f16)(k < TEMPD ? encWih[j * TEMPD + k]
                                     : encWhh[(size_t)j * HID + (k - TEMPD)]);
        Wdec0[idx] = (f16)(k < TEMPD ? decWih[j * (TEMPD + 1) + k]
                                     : decWhh[(size_t)j * HID + (k - TEMPD)]);
        if (idx < TEMPD * HID) fcWh[idx] = (f16)fcW[idx];
        if (idx < 4 * HID) {
            enc_b[idx] = encbih[idx] + encbhh[idx];
            dec_b[idx] = decbih[idx] + decbhh[idx];
            wlast[idx] = decWih[idx * (TEMPD + 1) + TEMPD];
        }
    }
}

// ---------------------------------------------------------------------------
// prep_fold: WdecF = decWhh + decWih_x @ fcW ; biasF = decb + decWih_x @ fcb
// ---------------------------------------------------------------------------
__global__ __launch_bounds__(256)
void prep_fold(
    const float* __restrict__ decWih, const float* __restrict__ decWhh,
    const float* __restrict__ decbih, const float* __restrict__ decbhh,
    const float* __restrict__ fcW,    const float* __restrict__ fcb,
    f16* __restrict__ WdecF, float* __restrict__ biasF)
{
    __shared__ float wih[16][TEMPD];
    __shared__ float fcbL[TEMPD];
    const int tid = threadIdx.x;
    const int j0  = blockIdx.x * 16;
    for (int i = tid; i < 16 * TEMPD; i += 256) {
        int r = i >> 7, p = i & 127;
        wih[r][p] = decWih[(size_t)(j0 + r) * (TEMPD + 1) + p];
    }
    if (tid < TEMPD) fcbL[tid] = fcb[tid];
    __syncthreads();
    for (int kk = 0; kk < 4; ++kk) {
        int k = kk * 256 + tid;
        float acc[16];
        #pragma unroll
        for (int r = 0; r < 16; ++r) acc[r] = decWhh[(size_t)(j0 + r) * HID + k];
        for (int p = 0; p < TEMPD; ++p) {
            float w = fcW[(size_t)p * HID + k];
            #pragma unroll
            for (int r = 0; r < 16; ++r) acc[r] += wih[r][p] * w;
        }
        #pragma unroll
        for (int r = 0; r < 16; ++r) WdecF[(size_t)(j0 + r) * HID + k] = (f16)acc[r];
    }
    if (tid < 16) {
        float b = decbih[j0 + tid] + decbhh[j0 + tid];
        for (int p = 0; p < TEMPD; ++p) b += wih[tid][p] * fcbL[p];
        biasF[j0 + tid] = b;
    }
}

// ---------------------------------------------------------------------------
// prep_tileW: merged W [4096][WS] -> fragment-ordered tiles.
// Frag flat index F = bn*NKC*16 + kc*16 + s*8 + g*2 + wc; half8 addr = F*64+lane.
// Lane holds W[g*1024 + bn*32 + wc*16 + (lane&15)][kc*64 + s*32 + (lane>>4)*8 ..+8].
// ---------------------------------------------------------------------------
__global__ void prep_tileW(const f16* __restrict__ Wsrc, f16* __restrict__ Wt,
                           int NKC, int WS)
{
    int idx = blockIdx.x * blockDim.x + threadIdx.x;
    int total = 32 * NKC * 16 * 64;
    if (idx >= total) return;
    int lane = idx & 63;
    int f    = idx >> 6;
    int wc   = f & 1;
    int g    = (f >> 1) & 3;
    int s    = (f >> 3) & 1;
    int kc   = (f >> 4) % NKC;
    int bn   = (f >> 4) / NKC;
    int row  = g * HID + bn * 32 + wc * 16 + (lane & 15);
    int k0   = kc * 64 + s * 32 + (lane >> 4) * 8;
    *(half8*)(Wt + (size_t)idx * 8) = *(const half8*)(Wsrc + (size_t)row * WS + k0);
}

// ---------------------------------------------------------------------------
// Fused LSTM step. Tile 128 rows x (4 gates x 32 cols). Grid 512 = 16bm x 32bn
// (XCD-swizzled so each XCD owns 4 bn panels -> W L2-resident).
// 256 threads = 4 waves (wr: 64-row half, wc: 16-col half).
// A staged in LDS (dbuf, glds, XOR-swizzle); W fragments register-double-
// buffered straight from L2 (tiled coalesced layout) -> LDS reads halved.
// FULLK: K=1152 (x f16 [2048][128] + h), else K=1024 (h only).
// ---------------------------------------------------------------------------
template <int FULLK, int DEC>
__global__ __launch_bounds__(256, 2)
void lstm_step(
    const f16* __restrict__ xsrc,
    const f16* __restrict__ h_in, f16* __restrict__ h_out, float* __restrict__ c,
    const f16* __restrict__ Wt,               // tiled fragments
    const float* __restrict__ bias,
    const float* __restrict__ wlast, const float* __restrict__ speeds, int m_step)
{
    constexpr int NKC = FULLK ? 18 : 16;

    __shared__ half8 ldsA[2][1024];   // 128 rows x 8 k-slots, swizzled (16KB x2)

    const int tid  = threadIdx.x;
    const int lane = tid & 63;
    const int wid  = tid >> 6;
    const int wr   = wid >> 1;        // 0..1 : 64-row half
    const int wc   = wid & 1;         // 0..1 : 16-col half
    const int id   = blockIdx.x;
    const int swzb = (id & 7) * 64 + (id >> 3);   // bijective (512 = 8*64)
    const int bn   = swzb >> 4;       // 0..31  (XCD x owns bn in [4x,4x+4))
    const int bm   = swzb & 15;       // 0..15

    // per-wave W fragment base (half8 units); frag addr = F*64+lane,
    // F = bn*NKC*16 + kc*16 + (s*4+g)*2 + wc  ->  wc term is wc*64  (r6 bug: wc*128)
    const half8* wtb = (const half8*)Wt + ((size_t)bn * NKC * 16) * 64 + wc * 64 + lane;

    f32x4 acc[4][4];                  // [gate][m_rep]
    #pragma unroll
    for (int g = 0; g < 4; ++g)
        #pragma unroll
        for (int mr = 0; mr < 4; ++mr)
            acc[g][mr] = (f32x4){0.f, 0.f, 0.f, 0.f};

    auto stageA = [&](int b, int kc) {
        if (FULLK && kc < 2) {
            #pragma unroll
            for (int it = 0; it < 4; ++it) {
                int p = wid * 256 + it * 64 + lane;
                int row = p >> 3, s = p & 7;
                gld16(xsrc + (size_t)(bm * 128 + row) * TEMPD + kc * 64 + ((s ^ (row & 7)) << 3),
                      &ldsA[b][wid * 256 + it * 64]);
            }
        } else {
            const int k0 = kc * 64 - (FULLK ? TEMPD : 0);
            #pragma unroll
            for (int it = 0; it < 4; ++it) {
                int p = wid * 256 + it * 64 + lane;
                int row = p >> 3, s = p & 7;
                gld16(h_in + (size_t)(bm * 128 + row) * HID + k0 + ((s ^ (row & 7)) << 3),
                      &ldsA[b][wid * 256 + it * 64]);
            }
        }
    };
    auto loadW = [&](half8 (&wf)[8], int kc) {
        const half8* p = wtb + (size_t)kc * (16 * 64);
        #pragma unroll
        for (int f = 0; f < 8; ++f) wf[f] = p[f * 128];   // f = s*4+g -> (s*8+g*2)*64
    };
    auto compute = [&](int b, const half8 (&wf)[8]) {
        #pragma unroll
        for (int s = 0; s < 2; ++s) {
            const int ks = s * 4 + (lane >> 4);
            half8 af[4];
            #pragma unroll
            for (int mr = 0; mr < 4; ++mr) {
                int row = wr * 64 + mr * 16 + (lane & 15);
                af[mr] = ldsA[b][row * 8 + (ks ^ (row & 7))];
            }
            __builtin_amdgcn_s_setprio(1);
            #pragma unroll
            for (int g = 0; g < 4; ++g)
                #pragma unroll
                for (int mr = 0; mr < 4; ++mr)
                    acc[g][mr] = __builtin_amdgcn_mfma_f32_16x16x32_f16(af[mr], wf[s * 4 + g], acc[g][mr], 0, 0, 0);
            __builtin_amdgcn_s_setprio(0);
        }
    };

    half8 wfA[8], wfB[8];             // named double buffers (static indexing)
    stageA(0, 0); loadW(wfA, 0);
    __syncthreads();

    for (int kc = 0; kc < NKC; kc += 2) {          // NKC even (18 or 16)
        stageA(1, kc + 1); loadW(wfB, kc + 1);
        compute(0, wfA);
        __syncthreads();
        if (kc + 2 < NKC) { stageA(0, kc + 2); loadW(wfA, kc + 2); }
        compute(1, wfB);
        __syncthreads();
    }

    // ---- epilogue: LSTM pointwise ----
    const int col_g = bn * 32 + wc * 16 + (lane & 15);
    const float bi  = bias[col_g];
    const float bf_ = bias[HID + col_g];
    const float bg  = bias[2 * HID + col_g];
    const float bo  = bias[3 * HID + col_g];
    float wli = 0.f, wlf = 0.f, wlg = 0.f, wlo = 0.f;
    if (DEC) {
        wli = wlast[col_g];
        wlf = wlast[HID + col_g];
        wlg = wlast[2 * HID + col_g];
        wlo = wlast[3 * HID + col_g];
    }
    #pragma unroll
    for (int mr = 0; mr < 4; ++mr) {
        #pragma unroll
        for (int q = 0; q < 4; ++q) {
            int row_g = bm * 128 + wr * 64 + mr * 16 + (lane >> 4) * 4 + q;
            float pi = acc[0][mr][q] + bi;
            float pf = acc[1][mr][q] + bf_;
            float pg = acc[2][mr][q] + bg;
            float po = acc[3][mr][q] + bo;
            if (DEC) {
                float sp = speeds[(size_t)row_g * M_DEC + m_step];
                pi += sp * wli; pf += sp * wlf; pg += sp * wlg; po += sp * wlo;
            }
            float ii = sigf(pi), ff = sigf(pf), gg = tanhf_(pg), oo = sigf(po);
            size_t idx = (size_t)row_g * HID + col_g;
            float cn = ff * c[idx] + ii * gg;
            c[idx] = cn;
            h_out[idx] = (f16)(oo * tanhf_(cn));
        }
    }
}

// ---------------------------------------------------------------------------
// Batched fc over 16 stored h slots: preds = h @ fcW^T + fcb -> d_out.
// ---------------------------------------------------------------------------
__global__ __launch_bounds__(256, 2)
void fc_batch(const f16* __restrict__ hist, const f16* __restrict__ fcWh,
              const float* __restrict__ fcb, float* __restrict__ out, int mbase)
{
    __shared__ half8 ldsA[32 * 8];
    __shared__ half8 ldsW[128 * 8];
    const int tid  = threadIdx.x;
    const int lane = tid & 63;
    const int wid  = tid >> 6;
    const int wr   = wid >> 1;
    const int wc   = wid & 1;
    const int bm   = blockIdx.x;
    const int slot = bm >> 6;
    const int b0   = (bm & 63) * 32;
    const f16* hrow = hist + (size_t)slot * (B_SZ * HID) + (size_t)b0 * HID;
    const int  mm   = mbase + slot;

    f32x4 acc[4];
    #pragma unroll
    for (int nr = 0; nr < 4; ++nr) acc[nr] = (f32x4){0.f, 0.f, 0.f, 0.f};

    for (int kc = 0; kc < HID / 64; ++kc) {
        const int k0 = kc * 64;
        {
            int row = tid >> 3, s = tid & 7;
            gld16(hrow + (size_t)row * HID + k0 + ((s ^ (row & 7)) << 3), &ldsA[wid * 64]);
        }
        #pragma unroll
        for (int it = 0; it < 4; ++it) {
            int p = wid * 256 + it * 64 + lane;
            int row = p >> 3, s = p & 7;
            gld16(fcWh + (size_t)row * HID + k0 + ((s ^ (row & 7)) << 3), &ldsW[wid * 256 + it * 64]);
        }
        __syncthreads();
        #pragma unroll
        for (int s2 = 0; s2 < 2; ++s2) {
            int arow = wr * 16 + (lane & 15);
            int slotk = s2 * 4 + (lane >> 4);
            half8 a = ldsA[arow * 8 + (slotk ^ (arow & 7))];
            #pragma unroll
            for (int nr = 0; nr < 4; ++nr) {
                int brow = wc * 64 + nr * 16 + (lane & 15);
                half8 bfr = ldsW[brow * 8 + (slotk ^ (brow & 7))];
                acc[nr] = __builtin_amdgcn_mfma_f32_16x16x32_f16(a, bfr, acc[nr], 0, 0, 0);
            }
        }
        __syncthreads();
    }
    #pragma unroll
    for (int nr = 0; nr < 4; ++nr)
        #pragma unroll
        for (int q = 0; q < 4; ++q) {
            int rloc = wr * 16 + (lane >> 4) * 4 + q;
            int col  = wc * 64 + nr * 16 + (lane & 15);
            out[(size_t)(b0 + rloc) * (M_DEC * TEMPD) + (size_t)mm * TEMPD + col] = acc[nr][q] + fcb[col];
        }
}

// ---------------------------------------------------------------------------
extern "C" void kernel_launch(void* const* d_in, const int* in_sizes, int n_in,
                              void* d_out, int out_size, void* d_ws, size_t ws_size,
                              hipStream_t stream)
{
    (void)in_sizes; (void)n_in; (void)out_size; (void)ws_size;
    const float* temp_seq   = (const float*)d_in[0];
    const float* avg_speeds = (const float*)d_in[1];
    const float* enc_Wih    = (const float*)d_in[2];
    const float* enc_Whh    = (const float*)d_in[3];
    const float* enc_bih    = (const float*)d_in[4];
    const float* enc_bhh    = (const float*)d_in[5];
    const float* dec_Wih    = (const float*)d_in[6];
    const float* dec_Whh    = (const float*)d_in[7];
    const float* dec_bih    = (const float*)d_in[8];
    const float* dec_bhh    = (const float*)d_in[9];
    const float* fc_W       = (const float*)d_in[10];
    const float* fc_b       = (const float*)d_in[11];
    float* out = (float*)d_out;

    char* ws = (char*)d_ws;
    size_t off = 0;
    auto alloc = [&](size_t bytes) -> void* {
        void* p = ws + off;
        off += (bytes + 255) & ~(size_t)255;
        return p;
    };
    const size_t SLOT = (size_t)B_SZ * HID;
    f16*   Wenc   = (f16*)alloc((size_t)4 * HID * (TEMPD + HID) * 2);
    f16*   Wdec0  = (f16*)alloc((size_t)4 * HID * (TEMPD + HID) * 2);
    f16*   WdecF  = (f16*)alloc((size_t)4 * HID * HID * 2);
    f16*   WencT  = (f16*)alloc((size_t)32 * 18 * 16 * 64 * 8 * 2);
    f16*   Wdec0T = (f16*)alloc((size_t)32 * 18 * 16 * 64 * 8 * 2);
    f16*   WdecFT = (f16*)alloc((size_t)32 * 16 * 16 * 64 * 8 * 2);
    f16*   fcWh   = (f16*)alloc((size_t)TEMPD * HID * 2);
    float* enc_b  = (float*)alloc((size_t)4 * HID * 4);
    float* dec_b  = (float*)alloc((size_t)4 * HID * 4);
    float* biasF  = (float*)alloc((size_t)4 * HID * 4);
    float* wlast  = (float*)alloc((size_t)4 * HID * 4);
    f16*   hA     = (f16*)alloc(SLOT * 2);
    f16*   hB     = (f16*)alloc(SLOT * 2);
    float* cbuf   = (float*)alloc(SLOT * 4);
    f16*   xseq   = (f16*)alloc((size_t)T_ENC * B_SZ * TEMPD * 2);   // 88 MB
    f16*   hist   = (f16*)alloc(16 * SLOT * 2);                      // 64 MB

    hipMemsetAsync(hA,   0, SLOT * 2, stream);
    hipMemsetAsync(cbuf, 0, SLOT * 4, stream);

    prep_xseq<<<(B_SZ * T_ENC * TEMPD / 4 + 255) / 256, 256, 0, stream>>>(temp_seq, xseq);
    prep_misc<<<8192, 256, 0, stream>>>(
        enc_Wih, enc_Whh, dec_Wih, dec_Whh,
        enc_bih, enc_bhh, dec_bih, dec_bhh, fc_W,
        Wenc, Wdec0, fcWh, enc_b, dec_b, wlast);
    prep_fold<<<256, 256, 0, stream>>>(
        dec_Wih, dec_Whh, dec_bih, dec_bhh, fc_W, fc_b, WdecF, biasF);
    prep_tileW<<<(32 * 18 * 16 * 64 + 255) / 256, 256, 0, stream>>>(Wenc,  WencT,  18, TEMPD + HID);
    prep_tileW<<<(32 * 18 * 16 * 64 + 255) / 256, 256, 0, stream>>>(Wdec0, Wdec0T, 18, TEMPD + HID);
    prep_tileW<<<(32 * 16 * 16 * 64 + 255) / 256, 256, 0, stream>>>(WdecF, WdecFT, 16, HID);

    f16* hbuf[2] = {hA, hB};
    for (int t = 0; t < T_ENC; ++t) {
        lstm_step<1, 0><<<512, 256, 0, stream>>>(
            xseq + (size_t)t * (B_SZ * TEMPD),
            hbuf[t & 1], hbuf[(t + 1) & 1], cbuf,
            WencT, enc_b, nullptr, nullptr, 0);
    }
    // T_ENC even -> final enc h is in hA; dec0 x = xseq last slice
    for (int m = 0; m < M_DEC; ++m) {
        const f16* hin = (m == 0) ? hA : hist + ((size_t)((m - 1) & 15)) * SLOT;
        f16* hout = hist + ((size_t)(m & 15)) * SLOT;
        if (m == 0) {
            lstm_step<1, 1><<<512, 256, 0, stream>>>(
                xseq + (size_t)(T_ENC - 1) * (B_SZ * TEMPD),
                hin, hout, cbuf, Wdec0T, dec_b, wlast, avg_speeds, 0);
        } else {
            lstm_step<0, 1><<<512, 256, 0, stream>>>(
                nullptr, hin, hout, cbuf, WdecFT, biasF, wlast, avg_speeds, m);
        }
        if ((m & 15) == 15) {
            fc_batch<<<1024, 256, 0, stream>>>(hist, fcWh, fc_b, out, m - 15);
        }
    }
}